// Round 3
// baseline (1746.868 us; speedup 1.0000x reference)
//
#include <hip/hip_runtime.h>
#include <cstdint>

#define T_TOK   16384
#define DM      1024
#define DFF     4096
#define NE      8

typedef unsigned short u16;
typedef __bf16 bf16x8 __attribute__((ext_vector_type(8)));
typedef float  f32x4  __attribute__((ext_vector_type(4)));
typedef u16    u16x4  __attribute__((ext_vector_type(4)));

__device__ __forceinline__ u16 f2bf(float f) {
  unsigned u = __float_as_uint(f);
  u = u + 0x7FFFu + ((u >> 16) & 1u);
  return (u16)(u >> 16);
}

// exact-GELU via A-S 7.1.26 erf (abs err 1.5e-7 << bf16 rounding)
__device__ __forceinline__ float gelu_exact(float v) {
  float x  = v * 0.70710678118654752f;
  float ax = fabsf(x);
  float t  = __builtin_amdgcn_rcpf(fmaf(0.3275911f, ax, 1.0f));
  float p  = fmaf(1.061405429f, t, -1.453152027f);
  p = fmaf(p, t, 1.421413741f);
  p = fmaf(p, t, -0.284496736f);
  p = fmaf(p, t, 0.254829592f);
  p = p * t;
  float e  = __expf(-x * x);
  float er = fmaf(-p, e, 1.0f);
  er = copysignf(er, x);
  return 0.5f * v * (1.0f + er);
}

__device__ __forceinline__ void async_copy16(void* lds, const void* g) {
  __builtin_amdgcn_global_load_lds(
      (const __attribute__((address_space(1))) unsigned int*)g,
      (__attribute__((address_space(3))) unsigned int*)lds, 16, 0, 0);
}

// ---------------- converts ----------------
__global__ __launch_bounds__(256) void convert_x_kernel(
    const float* __restrict__ x, u16* __restrict__ xb) {
  int i = blockIdx.x * 256 + threadIdx.x;
  float4 v = ((const float4*)x)[i];
  uint2 o;
  o.x = (unsigned)f2bf(v.x) | ((unsigned)f2bf(v.y) << 16);
  o.y = (unsigned)f2bf(v.z) | ((unsigned)f2bf(v.w) << 16);
  ((uint2*)xb)[i] = o;
}

// in: fp32 [E][R][C] -> out: bf16 [E][C][R]
__global__ __launch_bounds__(256) void transpose_convert_kernel(
    const float* __restrict__ in, u16* __restrict__ out, int R, int C) {
  __shared__ float tile[32][33];
  int e = blockIdx.z;
  int r0 = blockIdx.y * 32, c0 = blockIdx.x * 32;
  int tx = threadIdx.x, ty = threadIdx.y;           // (32, 8)
  const float* src = in + (size_t)e * R * C;
  u16* dst = out + (size_t)e * R * C;
  #pragma unroll
  for (int i = 0; i < 32; i += 8)
    tile[ty + i][tx] = src[(size_t)(r0 + ty + i) * C + (c0 + tx)];
  __syncthreads();
  #pragma unroll
  for (int i = 0; i < 32; i += 8)
    dst[(size_t)(c0 + ty + i) * R + (r0 + tx)] = f2bf(tile[tx][ty + i]);
}

// ---------------- router ----------------
__global__ __launch_bounds__(256) void router_kernel(
    const float* __restrict__ x, const float* __restrict__ wr,
    int* __restrict__ tok_e, float* __restrict__ tok_w,
    int* __restrict__ counts, float* __restrict__ psum) {
  __shared__ float ps[NE];
  __shared__ int   pc[NE];
  int tid = threadIdx.x, wave = tid >> 6, lane = tid & 63;
  if (tid < NE) { ps[tid] = 0.f; pc[tid] = 0; }
  __syncthreads();

  int t = blockIdx.x * 4 + wave;
  const float* xrow = x + (size_t)t * DM;
  float acc[NE];
  #pragma unroll
  for (int e = 0; e < NE; ++e) acc[e] = 0.f;
  for (int j = 0; j < DM / 64; ++j) {
    float xv = xrow[j * 64 + lane];
    const float* w = wr + (size_t)(j * 64 + lane) * NE;
    #pragma unroll
    for (int e = 0; e < NE; ++e) acc[e] += xv * w[e];
  }
  #pragma unroll
  for (int m = 1; m < 64; m <<= 1) {
    #pragma unroll
    for (int e = 0; e < NE; ++e) acc[e] += __shfl_xor(acc[e], m, 64);
  }
  if (lane == 0) {
    float mx = acc[0];
    #pragma unroll
    for (int e = 1; e < NE; ++e) mx = fmaxf(mx, acc[e]);
    float p[NE], s = 0.f;
    #pragma unroll
    for (int e = 0; e < NE; ++e) { p[e] = expf(acc[e] - mx); s += p[e]; }
    float inv = 1.f / s;
    int i1 = 0; float b1v = p[0];
    #pragma unroll
    for (int e = 1; e < NE; ++e) if (p[e] > b1v) { b1v = p[e]; i1 = e; }
    int i2 = -1; float b2v = -1.f;
    #pragma unroll
    for (int e = 0; e < NE; ++e) if (e != i1 && p[e] > b2v) { b2v = p[e]; i2 = e; }
    float wsum = b1v + b2v;
    tok_e[2 * t]     = i1;  tok_e[2 * t + 1] = i2;
    tok_w[2 * t]     = b1v / wsum;
    tok_w[2 * t + 1] = b2v / wsum;
    atomicAdd(&pc[i1], 1); atomicAdd(&pc[i2], 1);
    #pragma unroll
    for (int e = 0; e < NE; ++e) atomicAdd(&ps[e], p[e] * inv);
  }
  __syncthreads();
  if (tid < NE) { atomicAdd(&counts[tid], pc[tid]); atomicAdd(&psum[tid], ps[tid]); }
}

__global__ void scan_kernel(const int* __restrict__ counts, int* __restrict__ offsets) {
  if (threadIdx.x == 0) {
    int r = 0;
    for (int e = 0; e < NE; ++e) { offsets[e] = r; r += counts[e]; }
  }
}

__global__ __launch_bounds__(256) void build_lists_kernel(
    const int* __restrict__ tok_e, const float* __restrict__ tok_w,
    const int* __restrict__ offsets, int* __restrict__ fill,
    int* __restrict__ rowlist, float* __restrict__ roww, int* __restrict__ spos) {
  int t = blockIdx.x * 256 + threadIdx.x;
  #pragma unroll
  for (int s = 0; s < 2; ++s) {
    int e = tok_e[2 * t + s];
    int pos = atomicAdd(&fill[e], 1);
    int idx = offsets[e] + pos;
    rowlist[idx] = t;
    roww[idx] = tok_w[2 * t + s];
    spos[2 * t + s] = idx;
  }
}

// ---------------- expert GEMMs ----------------
// Operand-swapped MFMA: acc[p][q] = mfma(W_frag[p], X_frag[q]) so the C/D
// reg-index j maps to 4 CONSECUTIVE output columns (weight dim) -> packed
// vector stores in the epilogue.
// PASS 1: X = gathered xb rows (K=1024), W = W1T rows; h = gelu(XW+b1) bf16.
// PASS 2: X = h rows (K=4096), W = W2T rows; !ATOMIC: raw f32x4 -> Yout;
//         ATOMIC: atomicAdd(out, w*(y+b2)).
template <int PASS, bool ATOMIC>
__global__ __launch_bounds__(256) void moe_gemm_kernel(
    const u16* __restrict__ Asrc, const u16* __restrict__ BT,
    const float* __restrict__ bias,
    const int* __restrict__ counts, const int* __restrict__ offsets,
    const int* __restrict__ rowlist, const float* __restrict__ roww,
    u16* __restrict__ Hout, float* __restrict__ Yout, float* __restrict__ Out) {
  constexpr int K = (PASS == 1) ? DM : DFF;
  constexpr int N = (PASS == 1) ? DFF : DM;

  const int e = blockIdx.z;
  const int cnt = counts[e];
  const int row0 = blockIdx.y * 128;
  if (row0 >= cnt) return;
  const int off = offsets[e];
  const int nb = blockIdx.x * 128;
  const int tid = threadIdx.x, wave = tid >> 6, lane = tid & 63;

  __shared__ u16 lsA[128 * 64];
  __shared__ u16 lsB[128 * 64];

  // pre-swizzled global source chunk (linear LDS dest, swizzled ds_read)
  const int sw = (((lane & 7) ^ (lane >> 3)) * 8);
  const u16* aPtr[4];
  const u16* bPtr[4];
  #pragma unroll
  for (int i = 0; i < 4; ++i) {
    int rowi = (wave * 4 + i) * 8 + (lane >> 3);   // 0..127
    int r = row0 + rowi;
    int rr = (r < cnt) ? r : (cnt - 1);
    int srcrow;
    if (PASS == 1) srcrow = rowlist[off + rr];
    else           srcrow = off + rr;
    aPtr[i] = Asrc + (size_t)srcrow * K + sw;
    bPtr[i] = BT + ((size_t)e * N + (nb + rowi)) * K + sw;
  }

  f32x4 acc[4][4];   // [p = weight-dim frag][q = token-dim frag]
  #pragma unroll
  for (int p = 0; p < 4; ++p)
    #pragma unroll
    for (int q = 0; q < 4; ++q) acc[p][q] = (f32x4){0.f, 0.f, 0.f, 0.f};

  const int wu = wave >> 1, wv = wave & 1;  // wave's (weight, token) 64-blocks

  for (int kt = 0; kt < K; kt += 64) {
    #pragma unroll
    for (int i = 0; i < 4; ++i) {
      async_copy16(&lsA[(wave * 4 + i) * 512], aPtr[i] + kt);
      async_copy16(&lsB[(wave * 4 + i) * 512], bPtr[i] + kt);
    }
    __syncthreads();
    #pragma unroll
    for (int ks = 0; ks < 2; ++ks) {
      const int cbase = (((ks * 4 + (lane >> 4)) ^ (lane & 7)) * 8);
      bf16x8 wf[4], xf[4];
      #pragma unroll
      for (int p = 0; p < 4; ++p) {
        int rowW = wu * 64 + p * 16 + (lane & 15);
        wf[p] = *(const bf16x8*)&lsB[rowW * 64 + cbase];
      }
      #pragma unroll
      for (int q = 0; q < 4; ++q) {
        int rowX = wv * 64 + q * 16 + (lane & 15);
        xf[q] = *(const bf16x8*)&lsA[rowX * 64 + cbase];
      }
      #pragma unroll
      for (int p = 0; p < 4; ++p)
        #pragma unroll
        for (int q = 0; q < 4; ++q)
          acc[p][q] = __builtin_amdgcn_mfma_f32_16x16x32_bf16(wf[p], xf[q], acc[p][q], 0, 0, 0);
    }
    __syncthreads();
  }

  // epilogue: C'[u][v], u = weight col = (lane>>4)*4 + j (4 consecutive!),
  //           v = token row = lane&15
  if (PASS == 1) {
    #pragma unroll
    for (int p = 0; p < 4; ++p) {
      const int ub = nb + wu * 64 + p * 16 + ((lane >> 4) << 2);
      const float4 bv = *(const float4*)&bias[e * N + ub];
      #pragma unroll
      for (int q = 0; q < 4; ++q) {
        int v = row0 + wv * 64 + q * 16 + (lane & 15);
        if (v < cnt) {
          u16x4 o;
          o[0] = f2bf(gelu_exact(acc[p][q][0] + bv.x));
          o[1] = f2bf(gelu_exact(acc[p][q][1] + bv.y));
          o[2] = f2bf(gelu_exact(acc[p][q][2] + bv.z));
          o[3] = f2bf(gelu_exact(acc[p][q][3] + bv.w));
          *(u16x4*)&Hout[(size_t)(off + v) * DFF + ub] = o;
        }
      }
    }
  } else if (!ATOMIC) {
    #pragma unroll
    for (int p = 0; p < 4; ++p) {
      const int ub = nb + wu * 64 + p * 16 + ((lane >> 4) << 2);
      #pragma unroll
      for (int q = 0; q < 4; ++q) {
        int v = row0 + wv * 64 + q * 16 + (lane & 15);
        if (v < cnt)
          *(f32x4*)&Yout[(size_t)(off + v) * DM + ub] = acc[p][q];
      }
    }
  } else {
    #pragma unroll
    for (int p = 0; p < 4; ++p) {
      const int ub = nb + wu * 64 + p * 16 + ((lane >> 4) << 2);
      const float4 bv = *(const float4*)&bias[e * N + ub];
      #pragma unroll
      for (int q = 0; q < 4; ++q) {
        int v = row0 + wv * 64 + q * 16 + (lane & 15);
        if (v < cnt) {
          int t = rowlist[off + v];
          float w = roww[off + v];
          size_t base = (size_t)t * DM + ub;
          atomicAdd(&Out[base + 0], w * (acc[p][q][0] + bv.x));
          atomicAdd(&Out[base + 1], w * (acc[p][q][1] + bv.y));
          atomicAdd(&Out[base + 2], w * (acc[p][q][2] + bv.z));
          atomicAdd(&Out[base + 3], w * (acc[p][q][3] + bv.w));
        }
      }
    }
  }
}

// out[t] = w0*(y[s0]+b2[e0]) + w1*(y[s1]+b2[e1])
__global__ __launch_bounds__(256) void combine_kernel(
    const float* __restrict__ y, const int* __restrict__ spos,
    const int* __restrict__ tok_e, const float* __restrict__ tok_w,
    const float* __restrict__ b2, float* __restrict__ out) {
  int t = blockIdx.x;
  int c = threadIdx.x * 4;
  int p0 = spos[2 * t], p1 = spos[2 * t + 1];
  int e0 = tok_e[2 * t], e1 = tok_e[2 * t + 1];
  float w0 = tok_w[2 * t], w1 = tok_w[2 * t + 1];
  float4 a  = *(const float4*)&y[(size_t)p0 * DM + c];
  float4 b  = *(const float4*)&y[(size_t)p1 * DM + c];
  float4 ba = *(const float4*)&b2[e0 * DM + c];
  float4 bb = *(const float4*)&b2[e1 * DM + c];
  float4 o;
  o.x = w0 * (a.x + ba.x) + w1 * (b.x + bb.x);
  o.y = w0 * (a.y + ba.y) + w1 * (b.y + bb.y);
  o.z = w0 * (a.z + ba.z) + w1 * (b.z + bb.z);
  o.w = w0 * (a.w + ba.w) + w1 * (b.w + bb.w);
  *(float4*)&out[(size_t)t * DM + c] = o;
}

__global__ void aux_kernel(const int* __restrict__ counts, const float* __restrict__ psum,
                           float* __restrict__ out_aux) {
  if (threadIdx.x == 0) {
    float s = 0.f;
    for (int e = 0; e < NE; ++e)
      s += ((float)counts[e] / (float)(2 * T_TOK)) * (psum[e] / (float)T_TOK);
    *out_aux = (float)NE * 0.01f * s;
  }
}

// ---------------- host ----------------
extern "C" void kernel_launch(void* const* d_in, const int* in_sizes, int n_in,
                              void* d_out, int out_size, void* d_ws, size_t ws_size,
                              hipStream_t stream) {
  const float* x  = (const float*)d_in[0];
  const float* wr = (const float*)d_in[1];
  const float* W1 = (const float*)d_in[2];
  const float* b1 = (const float*)d_in[3];
  const float* W2 = (const float*)d_in[4];
  const float* b2 = (const float*)d_in[5];
  float* out = (float*)d_out;
  char* ws = (char*)d_ws;

  int*   counts  = (int*)(ws + 0);
  int*   fill    = (int*)(ws + 64);
  float* psum    = (float*)(ws + 128);
  int*   offsets = (int*)(ws + 192);
  int*   tok_e   = (int*)(ws + 256);
  float* tok_w   = (float*)(ws + 256 + 131072);
  int*   rowlist = (int*)(ws + 256 + 2 * 131072);
  float* roww    = (float*)(ws + 256 + 3 * 131072);
  int*   spos    = (int*)(ws + 256 + 4 * 131072);
  const size_t MiB = 1ull << 20;
  u16* xb  = (u16*)(ws + 1 * MiB);     // 32 MiB
  u16* W1T = (u16*)(ws + 33 * MiB);    // 64 MiB  [E][DFF][DM]
  u16* W2T = (u16*)(ws + 97 * MiB);    // 64 MiB  [E][DM][DFF]
  u16* h   = (u16*)(ws + 161 * MiB);   // 256 MiB [2T][DFF]
  float* y = (float*)(ws + 417 * MiB); // 128 MiB [2T][DM]

  const bool bigws = ws_size >= (size_t)545 * MiB;

  hipMemsetAsync(ws, 0, 256, stream);
  if (!bigws)
    hipMemsetAsync(d_out, 0, (size_t)out_size * sizeof(float), stream);

  convert_x_kernel<<<T_TOK * DM / 4 / 256, 256, 0, stream>>>(x, xb);
  transpose_convert_kernel<<<dim3(DFF / 32, DM / 32, NE), dim3(32, 8), 0, stream>>>(W1, W1T, DM, DFF);
  transpose_convert_kernel<<<dim3(DM / 32, DFF / 32, NE), dim3(32, 8), 0, stream>>>(W2, W2T, DFF, DM);
  router_kernel<<<T_TOK / 4, 256, 0, stream>>>(x, wr, tok_e, tok_w, counts, psum);
  scan_kernel<<<1, 64, 0, stream>>>(counts, offsets);
  build_lists_kernel<<<T_TOK / 256, 256, 0, stream>>>(tok_e, tok_w, offsets, fill, rowlist, roww, spos);
  moe_gemm_kernel<1, false><<<dim3(DFF / 128, T_TOK / 128, NE), 256, 0, stream>>>(
      xb, W1T, b1, counts, offsets, rowlist, roww, h, nullptr, nullptr);
  if (bigws) {
    moe_gemm_kernel<2, false><<<dim3(DM / 128, T_TOK / 128, NE), 256, 0, stream>>>(
        h, W2T, b2, counts, offsets, rowlist, roww, nullptr, y, nullptr);
    combine_kernel<<<T_TOK, 256, 0, stream>>>(y, spos, tok_e, tok_w, b2, out);
  } else {
    moe_gemm_kernel<2, true><<<dim3(DM / 128, T_TOK / 128, NE), 256, 0, stream>>>(
        h, W2T, b2, counts, offsets, rowlist, roww, nullptr, nullptr, out);
  }
  aux_kernel<<<1, 64, 0, stream>>>(counts, psum, out + (size_t)T_TOK * DM);
}